// Round 3
// baseline (365.609 us; speedup 1.0000x reference)
//
#include <hip/hip_runtime.h>

#define B_ 16
#define C_ 512
#define N_ 2048
#define D_ 64

typedef unsigned short u16;
typedef unsigned int   u32;
typedef __bf16 bfv4 __attribute__((ext_vector_type(4)));
typedef __bf16 bfv8 __attribute__((ext_vector_type(8)));
typedef float  f4   __attribute__((ext_vector_type(4)));
typedef float  f16v __attribute__((ext_vector_type(16)));

__device__ __forceinline__ u16 f2bf(float f) {
  u32 u = __float_as_uint(f);
  u32 r = (u + 0x7FFFu + ((u >> 16) & 1u)) >> 16;   // RNE
  return (u16)r;
}
__device__ __forceinline__ u32 pack2(float a, float b) {
  return (u32)f2bf(a) | ((u32)f2bf(b) << 16);
}
// 8-byte-aligned LDS load of 8 bf16 (2 x ds_read_b64)
__device__ __forceinline__ bfv8 ld8(const u16* p) {
  bfv4 lo = *(const bfv4*)p;
  bfv4 hi = *(const bfv4*)(p + 4);
  bfv8 r;
  r[0] = lo[0]; r[1] = lo[1]; r[2] = lo[2]; r[3] = lo[3];
  r[4] = hi[0]; r[5] = hi[1]; r[6] = hi[2]; r[7] = hi[3];
  return r;
}

// ---------------- all W -> bf16, one launch ----------------
__global__ __launch_bounds__(256) void conv_all(
    const float* __restrict__ Wq, const float* __restrict__ Wk,
    const float* __restrict__ Wv,
    u16* __restrict__ Wqb, u16* __restrict__ Wkb, u16* __restrict__ Wvb) {
  const int q4 = D_ * C_ / 4;   // 8192
  const int v4 = C_ * C_ / 4;   // 65536
  int i = blockIdx.x * 256 + threadIdx.x;
  const float* src; u16* dst; int j;
  if (i < q4)            { src = Wq; dst = Wqb; j = i; }
  else if (i < 2 * q4)   { src = Wk; dst = Wkb; j = i - q4; }
  else                   { j = i - 2 * q4; if (j >= v4) return; src = Wv; dst = Wvb; }
  float4 v = ((const float4*)src)[j];
  ((uint2*)dst)[j] = make_uint2(pack2(v.x, v.y), pack2(v.z, v.w));
}

// ---------------- fused transpose + Q/K/V projection ----------------
// Block (b, n0): stage x[b][:][n0..n0+63] transposed to LDS bf16, then
// QK proj (16x16x32) and V proj (32x32x16) straight out of LDS.
#define XS_STR 516   // u16 row stride: 258 dwords -> 2-way bank pattern (free)
__global__ __launch_bounds__(256, 2) void proj_all(
    const float* __restrict__ x,
    const u16* __restrict__ Wqb, const u16* __restrict__ Wkb,
    const float* __restrict__ bq, const float* __restrict__ bk,
    const u16* __restrict__ Wvb, const float* __restrict__ bv,
    u16* __restrict__ Qb, u16* __restrict__ Kb, u16* __restrict__ Vb) {
  __shared__ u16 xs[64][XS_STR];    // [n][c]
  const int b = blockIdx.x, n0 = blockIdx.y * 64;
  const int t = threadIdx.x;
  const int w = t >> 6, lane = t & 63;
  const int l15 = lane & 15, quad = lane >> 4;
  const int l31 = lane & 31, h = lane >> 5;

  // ---- stage + transpose: 16 passes x (16 n-float4 x 16 c-pairs) ----
  {
    const int n4 = t & 15, cp = t >> 4;
    for (int p = 0; p < 16; p++) {
      int c = p * 32 + cp * 2;
      const size_t rb = ((size_t)(b * C_) + c) * N_ + n0 + n4 * 4;
      float4 a = *(const float4*)&x[rb];
      float4 bb = *(const float4*)&x[rb + N_];
      *(u32*)&xs[n4 * 4 + 0][c] = pack2(a.x, bb.x);
      *(u32*)&xs[n4 * 4 + 1][c] = pack2(a.y, bb.y);
      *(u32*)&xs[n4 * 4 + 2][c] = pack2(a.z, bb.z);
      *(u32*)&xs[n4 * 4 + 3][c] = pack2(a.w, bb.w);
    }
  }
  __syncthreads();

  // ---- Q/K: wave w owns n-subtile w*16 ----
  {
    f4 accQ[4], accK[4];
#pragma unroll
    for (int mt = 0; mt < 4; mt++) { accQ[mt] = (f4)(0.0f); accK[mt] = (f4)(0.0f); }
    const u16* xrow = &xs[w * 16 + l15][0];
    for (int kc = 0; kc < 16; kc++) {
      bfv8 bx = ld8(&xrow[kc * 32 + quad * 8]);
#pragma unroll
      for (int mt = 0; mt < 4; mt++) {
        bfv8 aq = *(const bfv8*)&Wqb[(size_t)(mt * 16 + l15) * C_ + kc * 32 + quad * 8];
        bfv8 ak = *(const bfv8*)&Wkb[(size_t)(mt * 16 + l15) * C_ + kc * 32 + quad * 8];
        accQ[mt] = __builtin_amdgcn_mfma_f32_16x16x32_bf16(aq, bx, accQ[mt], 0, 0, 0);
        accK[mt] = __builtin_amdgcn_mfma_f32_16x16x32_bf16(ak, bx, accK[mt], 0, 0, 0);
      }
    }
    const size_t orow = ((size_t)(b * N_) + n0 + w * 16 + l15) * D_;
#pragma unroll
    for (int mt = 0; mt < 4; mt++) {
      f4 bq4 = *(const f4*)&bq[mt * 16 + quad * 4];
      f4 bk4 = *(const f4*)&bk[mt * 16 + quad * 4];
      *(uint2*)&Qb[orow + mt * 16 + quad * 4] =
          make_uint2(pack2(accQ[mt][0] + bq4[0], accQ[mt][1] + bq4[1]),
                     pack2(accQ[mt][2] + bq4[2], accQ[mt][3] + bq4[3]));
      *(uint2*)&Kb[orow + mt * 16 + quad * 4] =
          make_uint2(pack2(accK[mt][0] + bk4[0], accK[mt][1] + bk4[1]),
                     pack2(accK[mt][2] + bk4[2], accK[mt][3] + bk4[3]));
    }
  }

  // ---- V: wave w owns c-range w*128, 4 mt x 2 nt of 32x32x16 ----
  {
    f16v acc[4][2];
#pragma unroll
    for (int mt = 0; mt < 4; mt++)
#pragma unroll
      for (int nt = 0; nt < 2; nt++) acc[mt][nt] = (f16v)(0.0f);
    for (int kc = 0; kc < 32; kc++) {
      bfv8 bx[2];
#pragma unroll
      for (int nt = 0; nt < 2; nt++)
        bx[nt] = ld8(&xs[nt * 32 + l31][kc * 16 + h * 8]);
#pragma unroll
      for (int mt = 0; mt < 4; mt++) {
        bfv8 a = *(const bfv8*)&Wvb[(size_t)(w * 128 + mt * 32 + l31) * C_ + kc * 16 + h * 8];
#pragma unroll
        for (int nt = 0; nt < 2; nt++)
          acc[mt][nt] = __builtin_amdgcn_mfma_f32_32x32x16_bf16(a, bx[nt], acc[mt][nt], 0, 0, 0);
      }
    }
#pragma unroll
    for (int mt = 0; mt < 4; mt++)
#pragma unroll
      for (int nt = 0; nt < 2; nt++)
#pragma unroll
        for (int g = 0; g < 4; g++) {
          f4 bv4 = *(const f4*)&bv[w * 128 + mt * 32 + g * 8 + h * 4];
#pragma unroll
          for (int r = 0; r < 4; r++) {
            int c = w * 128 + mt * 32 + g * 8 + h * 4 + r;
            Vb[((size_t)(b * C_) + c) * N_ + n0 + nt * 32 + l31] =
                f2bf(acc[mt][nt][g * 4 + r] + bv4[r]);
          }
        }
  }
}

// ---------------- fused attention v3 ----------------
// Grid (N/64, B, 2): block = 64 i-rows x 256 c-cols. Per-wave acc shrinks
// 128 -> 64 regs so total regs fit 3 waves/SIMD; LDS 50.4 KB -> 3 blocks/CU
// (12 waves/CU vs 8). K double-buffered in VGPRs (kreg) so E-MFMA never
// waits on a cold L2/L3 load. V staged per-wave via global_load_lds with
// XOR chunk swizzle on the global source (read side undoes it).
// Grid is i0-fastest so same-(b,ch) blocks (sharing V slice + K) are
// temporally adjacent for L2 locality.
#define PS_STR 68   // u16: 34 dwords -> 2-way bank pattern (free)

__device__ __forceinline__ void stage_v(const u16* p0, u16* vsw, int j0) {
#pragma unroll
  for (int s = 0; s < 8; s++) {
    __builtin_amdgcn_global_load_lds(
        (const __attribute__((address_space(1))) void*)(p0 + (size_t)s * 8 * N_ + j0),
        (__attribute__((address_space(3))) void*)(vsw + s * 512),
        16, 0, 0);
  }
}

__global__ __launch_bounds__(256, 3) void attn(
    const float* __restrict__ x, const u16* __restrict__ Qb,
    const u16* __restrict__ Kb, const u16* __restrict__ Vb,
    const float* __restrict__ gamma, float* __restrict__ out) {
  __shared__ u16 Vs[4][64][64];        // [wave][c_local][j], swizzled chunks
  __shared__ u16 Ps[2][64][PS_STR];    // [buf][i][j]
  __shared__ float invl[64];
  const int i0 = blockIdx.x * 64, b = blockIdx.y, ch = blockIdx.z;
  const int t = threadIdx.x, w = t >> 6, lane = t & 63;
  const int l15 = lane & 15, quad = lane >> 4;
  const int l31 = lane & 31, h = lane >> 5;

  // V staging geometry: lane = r*8 + xchunk; LDS[row][x] = G[row][x ^ (row&7)]
  const int sr = lane >> 3;            // row within 8-row group
  const int sx = lane & 7;             // chunk slot
  const int cbase = ch * 256 + w * 64; // this wave's c-slice
  const u16* p0 = &Vb[((size_t)(b * C_) + cbase + sr) * N_ + ((sx ^ sr) << 3)];
  u16* vsw = &Vs[w][0][0];

  stage_v(p0, vsw, 0);                 // prefetch first V tile (async)

  bfv8 qf[2];                          // [kc], wave's 16 i-rows
#pragma unroll
  for (int kc = 0; kc < 2; kc++)
    qf[kc] = *(const bfv8*)&Qb[((size_t)(b * N_) + i0 + w * 16 + l15) * D_ + kc * 32 + quad * 8];

  // K double-buffer in regs: kreg[jt][kc] holds tile j0's K fragments
  const u16* Kbb = &Kb[(size_t)(b * N_) * D_];
  bfv8 kreg[4][2];
#pragma unroll
  for (int jt = 0; jt < 4; jt++)
#pragma unroll
    for (int kc = 0; kc < 2; kc++)
      kreg[jt][kc] = *(const bfv8*)&Kbb[(size_t)(jt * 16 + l15) * D_ + kc * 32 + quad * 8];

  f16v acc[2][2];   // mt: i = mt*32.., nt: c = cbase + nt*32..
#pragma unroll
  for (int mt = 0; mt < 2; mt++)
#pragma unroll
    for (int nt = 0; nt < 2; nt++) acc[mt][nt] = (f16v)(0.0f);
  float la = 0.0f;
  const int swz = l31 & 7;

  int buf = 0;
  for (int j0 = 0; j0 < N_; j0 += 64, buf ^= 1) {
    const int jn = (j0 + 64) & (N_ - 1);   // next tile (wraps harmlessly)
    // ---- E^T: wave w computes cols i = w*16..+16, all 64 j ----
#pragma unroll
    for (int jt = 0; jt < 4; jt++) {
      f4 e = (f4)(0.0f);
      e = __builtin_amdgcn_mfma_f32_16x16x32_bf16(kreg[jt][0], qf[0], e, 0, 0, 0);
      e = __builtin_amdgcn_mfma_f32_16x16x32_bf16(kreg[jt][1], qf[1], e, 0, 0, 0);
      // prefetch next tile's K fragment for this jt (hidden under exp/pack)
#pragma unroll
      for (int kc = 0; kc < 2; kc++)
        kreg[jt][kc] = *(const bfv8*)&Kbb[(size_t)(jn + jt * 16 + l15) * D_ + kc * 32 + quad * 8];
      float p0_ = __expf(e[0]), p1_ = __expf(e[1]);
      float p2_ = __expf(e[2]), p3_ = __expf(e[3]);
      la += (p0_ + p1_) + (p2_ + p3_);
      *(uint2*)&Ps[buf][w * 16 + l15][jt * 16 + quad * 4] =
          make_uint2(pack2(p0_, p1_), pack2(p2_, p3_));
    }
    // barrier: Ps[buf] published; implicit vmcnt(0) drain completes V stage
    __syncthreads();

    // ---- PV: A = P (LDS, all 64 i), B = V (LDS, own 64-c slice) ----
    __builtin_amdgcn_s_setprio(1);
#pragma unroll
    for (int kc = 0; kc < 4; kc++) {
      bfv8 pa[2];
#pragma unroll
      for (int mt = 0; mt < 2; mt++)
        pa[mt] = ld8(&Ps[buf][mt * 32 + l31][kc * 16 + h * 8]);
      bfv8 vb[2];
#pragma unroll
      for (int nt = 0; nt < 2; nt++)
        vb[nt] = *(const bfv8*)&vsw[(nt * 32 + l31) * 64 + (((kc * 2 + h) ^ swz) << 3)];
#pragma unroll
      for (int mt = 0; mt < 2; mt++)
#pragma unroll
        for (int nt = 0; nt < 2; nt++)
          acc[mt][nt] = __builtin_amdgcn_mfma_f32_32x32x16_bf16(pa[mt], vb[nt], acc[mt][nt], 0, 0, 0);
    }
    __builtin_amdgcn_s_setprio(0);
    // pin: stage must not be hoisted above the Vs ds_reads it overwrites
    __builtin_amdgcn_sched_barrier(0);
    if (j0 + 64 < N_) stage_v(p0, vsw, j0 + 64);   // async prefetch next tile
  }

  la += __shfl_xor(la, 16, 64);
  la += __shfl_xor(la, 32, 64);
  if (lane < 16) invl[w * 16 + l15] = 1.0f / la;
  __syncthreads();

  const float gam = gamma[0];
#pragma unroll
  for (int mt = 0; mt < 2; mt++)
#pragma unroll
    for (int nt = 0; nt < 2; nt++) {
      int c = cbase + nt * 32 + l31;
#pragma unroll
      for (int g = 0; g < 4; g++) {
        int ib = mt * 32 + g * 8 + h * 4;
        f4 il = *(const f4*)&invl[ib];
        size_t off = ((size_t)(b * C_) + c) * N_ + i0 + ib;
        f4 xv = *(const f4*)&x[off];
        f4 o;
#pragma unroll
        for (int r = 0; r < 4; r++)
          o[r] = xv[r] + gam * acc[mt][nt][g * 4 + r] * il[r];
        *(f4*)&out[off] = o;
      }
    }
}

extern "C" void kernel_launch(void* const* d_in, const int* in_sizes, int n_in,
                              void* d_out, int out_size, void* d_ws, size_t ws_size,
                              hipStream_t stream) {
  const float* x     = (const float*)d_in[0];
  const float* Wq    = (const float*)d_in[1];
  const float* bq    = (const float*)d_in[2];
  const float* Wk    = (const float*)d_in[3];
  const float* bk    = (const float*)d_in[4];
  const float* Wv    = (const float*)d_in[5];
  const float* bv    = (const float*)d_in[6];
  const float* gamma = (const float*)d_in[7];
  float* out = (float*)d_out;

  u16* wsu = (u16*)d_ws;
  u16* Qb  = wsu;                                   // B*N*D
  u16* Kb  = Qb  + (size_t)B_ * N_ * D_;            // B*N*D
  u16* Vb  = Kb  + (size_t)B_ * N_ * D_;            // B*C*N
  u16* Wqb = Vb  + (size_t)B_ * C_ * N_;            // D*C
  u16* Wkb = Wqb + (size_t)D_ * C_;                 // D*C
  u16* Wvb = Wkb + (size_t)D_ * C_;                 // C*C

  conv_all<<<dim3(320), 256, 0, stream>>>(Wq, Wk, Wv, Wqb, Wkb, Wvb);
  proj_all<<<dim3(B_, N_ / 64), 256, 0, stream>>>(x, Wqb, Wkb, bq, bk, Wvb, bv, Qb, Kb, Vb);
  attn<<<dim3(N_ / 64, B_, 2), 256, 0, stream>>>(x, Qb, Kb, Vb, gamma, out);
}

// Round 4
// 274.861 us; speedup vs baseline: 1.3302x; 1.3302x over previous
//
#include <hip/hip_runtime.h>

#define B_ 16
#define C_ 512
#define N_ 2048
#define D_ 64

typedef unsigned short u16;
typedef unsigned int   u32;
typedef __bf16 bfv4 __attribute__((ext_vector_type(4)));
typedef __bf16 bfv8 __attribute__((ext_vector_type(8)));
typedef float  f4   __attribute__((ext_vector_type(4)));
typedef float  f16v __attribute__((ext_vector_type(16)));

__device__ __forceinline__ u16 f2bf(float f) {
  u32 u = __float_as_uint(f);
  u32 r = (u + 0x7FFFu + ((u >> 16) & 1u)) >> 16;   // RNE
  return (u16)r;
}
__device__ __forceinline__ u32 pack2(float a, float b) {
  return (u32)f2bf(a) | ((u32)f2bf(b) << 16);
}
// 8-byte-aligned LDS load of 8 bf16 (2 x ds_read_b64)
__device__ __forceinline__ bfv8 ld8(const u16* p) {
  bfv4 lo = *(const bfv4*)p;
  bfv4 hi = *(const bfv4*)(p + 4);
  bfv8 r;
  r[0] = lo[0]; r[1] = lo[1]; r[2] = lo[2]; r[3] = lo[3];
  r[4] = hi[0]; r[5] = hi[1]; r[6] = hi[2]; r[7] = hi[3];
  return r;
}

// ---------------- all W -> bf16, one launch ----------------
__global__ __launch_bounds__(256) void conv_all(
    const float* __restrict__ Wq, const float* __restrict__ Wk,
    const float* __restrict__ Wv,
    u16* __restrict__ Wqb, u16* __restrict__ Wkb, u16* __restrict__ Wvb) {
  const int q4 = D_ * C_ / 4;   // 8192
  const int v4 = C_ * C_ / 4;   // 65536
  int i = blockIdx.x * 256 + threadIdx.x;
  const float* src; u16* dst; int j;
  if (i < q4)            { src = Wq; dst = Wqb; j = i; }
  else if (i < 2 * q4)   { src = Wk; dst = Wkb; j = i - q4; }
  else                   { j = i - 2 * q4; if (j >= v4) return; src = Wv; dst = Wvb; }
  float4 v = ((const float4*)src)[j];
  ((uint2*)dst)[j] = make_uint2(pack2(v.x, v.y), pack2(v.z, v.w));
}

// ---------------- fused transpose + Q/K/V projection v2 ----------------
// Latency-serialization fixes:
//  - QK phase: waves split by d (not n): weight-load instrs 128 -> 32 per
//    wave, zero cross-wave duplication (was 4x on the same 128 KB).
//  - V phase: explicit 2-deep register double-buffer on Wv fragments so
//    the kc loop's load->MFMA chain pipelines.
//  - stage loop: unroll 2 so next pass's x loads issue early.
#define XS_STR 516   // u16 row stride: 258 dwords -> 2-way bank pattern (free)
__global__ __launch_bounds__(256, 2) void proj_all(
    const float* __restrict__ x,
    const u16* __restrict__ Wqb, const u16* __restrict__ Wkb,
    const float* __restrict__ bq, const float* __restrict__ bk,
    const u16* __restrict__ Wvb, const float* __restrict__ bv,
    u16* __restrict__ Qb, u16* __restrict__ Kb, u16* __restrict__ Vb) {
  __shared__ u16 xs[64][XS_STR];    // [n][c]
  const int b = blockIdx.x, n0 = blockIdx.y * 64;
  const int t = threadIdx.x;
  const int w = t >> 6, lane = t & 63;
  const int l15 = lane & 15, quad = lane >> 4;
  const int l31 = lane & 31, h = lane >> 5;

  // ---- stage + transpose: 16 passes x (16 n-float4 x 16 c-pairs) ----
  {
    const int n4 = t & 15, cp = t >> 4;
#pragma unroll 2
    for (int p = 0; p < 16; p++) {
      int c = p * 32 + cp * 2;
      const size_t rb = ((size_t)(b * C_) + c) * N_ + n0 + n4 * 4;
      float4 a = *(const float4*)&x[rb];
      float4 bb = *(const float4*)&x[rb + N_];
      *(u32*)&xs[n4 * 4 + 0][c] = pack2(a.x, bb.x);
      *(u32*)&xs[n4 * 4 + 1][c] = pack2(a.y, bb.y);
      *(u32*)&xs[n4 * 4 + 2][c] = pack2(a.z, bb.z);
      *(u32*)&xs[n4 * 4 + 3][c] = pack2(a.w, bb.w);
    }
  }
  __syncthreads();

  // ---- Q/K: wave w owns d-rows w*16..+16; nt iterates the 4 n-subtiles ----
  {
    f4 accQ[4], accK[4];
#pragma unroll
    for (int nt = 0; nt < 4; nt++) { accQ[nt] = (f4)(0.0f); accK[nt] = (f4)(0.0f); }
    const u16* wqrow = &Wqb[(size_t)(w * 16 + l15) * C_];
    const u16* wkrow = &Wkb[(size_t)(w * 16 + l15) * C_];
    bfv8 aq = *(const bfv8*)&wqrow[quad * 8];
    bfv8 ak = *(const bfv8*)&wkrow[quad * 8];
    for (int kc = 0; kc < 16; kc++) {
      const int kn = (kc + 1) & 15;            // wrap: avoids OOB tail read
      bfv8 aqn = *(const bfv8*)&wqrow[kn * 32 + quad * 8];
      bfv8 akn = *(const bfv8*)&wkrow[kn * 32 + quad * 8];
#pragma unroll
      for (int nt = 0; nt < 4; nt++) {
        bfv8 bx = ld8(&xs[nt * 16 + l15][kc * 32 + quad * 8]);
        accQ[nt] = __builtin_amdgcn_mfma_f32_16x16x32_bf16(aq, bx, accQ[nt], 0, 0, 0);
        accK[nt] = __builtin_amdgcn_mfma_f32_16x16x32_bf16(ak, bx, accK[nt], 0, 0, 0);
      }
      aq = aqn; ak = akn;
    }
    // C layout: col(n) = l15, row(d) = quad*4 + reg  (within wave's d-slice)
    f4 bq4 = *(const f4*)&bq[w * 16 + quad * 4];
    f4 bk4 = *(const f4*)&bk[w * 16 + quad * 4];
#pragma unroll
    for (int nt = 0; nt < 4; nt++) {
      const size_t orow = ((size_t)(b * N_) + n0 + nt * 16 + l15) * D_ + w * 16 + quad * 4;
      *(uint2*)&Qb[orow] =
          make_uint2(pack2(accQ[nt][0] + bq4[0], accQ[nt][1] + bq4[1]),
                     pack2(accQ[nt][2] + bq4[2], accQ[nt][3] + bq4[3]));
      *(uint2*)&Kb[orow] =
          make_uint2(pack2(accK[nt][0] + bk4[0], accK[nt][1] + bk4[1]),
                     pack2(accK[nt][2] + bk4[2], accK[nt][3] + bk4[3]));
    }
  }

  // ---- V: wave w owns c-range w*128; 2-deep Wv fragment pipeline ----
  {
    f16v acc[4][2];
#pragma unroll
    for (int mt = 0; mt < 4; mt++)
#pragma unroll
      for (int nt = 0; nt < 2; nt++) acc[mt][nt] = (f16v)(0.0f);
    const u16* wvrow[4];
#pragma unroll
    for (int mt = 0; mt < 4; mt++)
      wvrow[mt] = &Wvb[(size_t)(w * 128 + mt * 32 + l31) * C_ + h * 8];

    bfv8 acur[4], anxt[4];
#pragma unroll
    for (int mt = 0; mt < 4; mt++) acur[mt] = *(const bfv8*)&wvrow[mt][0];

    for (int kc2 = 0; kc2 < 16; kc2++) {
      // step A: compute kc = 2*kc2 with acur, prefetch 2*kc2+1 into anxt
      {
        const int kc = 2 * kc2;
#pragma unroll
        for (int mt = 0; mt < 4; mt++)
          anxt[mt] = *(const bfv8*)&wvrow[mt][(kc + 1) * 16];
        bfv8 bx0 = ld8(&xs[l31][kc * 16 + h * 8]);
        bfv8 bx1 = ld8(&xs[32 + l31][kc * 16 + h * 8]);
#pragma unroll
        for (int mt = 0; mt < 4; mt++) {
          acc[mt][0] = __builtin_amdgcn_mfma_f32_32x32x16_bf16(acur[mt], bx0, acc[mt][0], 0, 0, 0);
          acc[mt][1] = __builtin_amdgcn_mfma_f32_32x32x16_bf16(acur[mt], bx1, acc[mt][1], 0, 0, 0);
        }
      }
      // step B: compute kc = 2*kc2+1 with anxt, prefetch next into acur
      {
        const int kc = 2 * kc2 + 1;
        const int kn = (kc + 1) & 31;          // wrap: avoids OOB tail read
#pragma unroll
        for (int mt = 0; mt < 4; mt++)
          acur[mt] = *(const bfv8*)&wvrow[mt][kn * 16];
        bfv8 bx0 = ld8(&xs[l31][kc * 16 + h * 8]);
        bfv8 bx1 = ld8(&xs[32 + l31][kc * 16 + h * 8]);
#pragma unroll
        for (int mt = 0; mt < 4; mt++) {
          acc[mt][0] = __builtin_amdgcn_mfma_f32_32x32x16_bf16(anxt[mt], bx0, acc[mt][0], 0, 0, 0);
          acc[mt][1] = __builtin_amdgcn_mfma_f32_32x32x16_bf16(anxt[mt], bx1, acc[mt][1], 0, 0, 0);
        }
      }
    }
#pragma unroll
    for (int mt = 0; mt < 4; mt++)
#pragma unroll
      for (int nt = 0; nt < 2; nt++)
#pragma unroll
        for (int g = 0; g < 4; g++) {
          f4 bv4 = *(const f4*)&bv[w * 128 + mt * 32 + g * 8 + h * 4];
#pragma unroll
          for (int r = 0; r < 4; r++) {
            int c = w * 128 + mt * 32 + g * 8 + h * 4 + r;
            Vb[((size_t)(b * C_) + c) * N_ + n0 + nt * 32 + l31] =
                f2bf(acc[mt][nt][g * 4 + r] + bv4[r]);
          }
        }
  }
}

// ---------------- fused attention v2 (round-2 proven: 141 us) ----------------
// Grid (B, N/128, 2): block = 128 i-rows x 256 c-cols. V staged per-wave via
// global_load_lds with XOR chunk swizzle on the global source.
#define PS_STR 68   // u16: 34 dwords -> 2-way bank pattern (free)

__device__ __forceinline__ void stage_v(const u16* p0, u16* vsw, int j0) {
#pragma unroll
  for (int s = 0; s < 8; s++) {
    __builtin_amdgcn_global_load_lds(
        (const __attribute__((address_space(1))) void*)(p0 + (size_t)s * 8 * N_ + j0),
        (__attribute__((address_space(3))) void*)(vsw + s * 512),
        16, 0, 0);
  }
}

__global__ __launch_bounds__(256, 2) void attn(
    const float* __restrict__ x, const u16* __restrict__ Qb,
    const u16* __restrict__ Kb, const u16* __restrict__ Vb,
    const float* __restrict__ gamma, float* __restrict__ out) {
  __shared__ u16 Vs[4][64][64];        // [wave][c_local][j], swizzled chunks
  __shared__ u16 Ps[2][128][PS_STR];   // [buf][i][j]
  __shared__ float invl[128];
  const int b = blockIdx.x, i0 = blockIdx.y * 128, ch = blockIdx.z;
  const int t = threadIdx.x, w = t >> 6, lane = t & 63;
  const int l15 = lane & 15, quad = lane >> 4;
  const int l31 = lane & 31, h = lane >> 5;

  // V staging geometry: lane = r*8 + xchunk; LDS[row][x] = G[row][x ^ (row&7)]
  const int sr = lane >> 3;            // row within 8-row group
  const int sx = lane & 7;             // chunk slot
  const int cbase = ch * 256 + w * 64; // this wave's c-slice
  const u16* p0 = &Vb[((size_t)(b * C_) + cbase + sr) * N_ + ((sx ^ sr) << 3)];
  u16* vsw = &Vs[w][0][0];

  stage_v(p0, vsw, 0);                 // prefetch first V tile (async)

  bfv8 qf[2][2];                       // [isub][kc]
#pragma unroll
  for (int isub = 0; isub < 2; isub++)
#pragma unroll
    for (int kc = 0; kc < 2; kc++)
      qf[isub][kc] = *(const bfv8*)&Qb[((size_t)(b * N_) + i0 + w * 32 + isub * 16 + l15) * D_ +
                                       kc * 32 + quad * 8];

  f16v acc[4][2];   // mt: i = mt*32.., nt: c = cbase + nt*32..
#pragma unroll
  for (int mt = 0; mt < 4; mt++)
#pragma unroll
    for (int nt = 0; nt < 2; nt++) acc[mt][nt] = (f16v)(0.0f);
  float la0 = 0.0f, la1 = 0.0f;
  const int swz = l31 & 7;

  int buf = 0;
  for (int j0 = 0; j0 < N_; j0 += 64, buf ^= 1) {
    // ---- E^T: wave w computes cols i = w*32..+32 (2 subtiles), all 64 j ----
#pragma unroll
    for (int jt = 0; jt < 4; jt++) {
      const u16* krow = &Kb[((size_t)(b * N_) + j0 + jt * 16 + l15) * D_];
      bfv8 kf0 = *(const bfv8*)&krow[quad * 8];
      bfv8 kf1 = *(const bfv8*)&krow[32 + quad * 8];
      f4 e0 = (f4)(0.0f), e1 = (f4)(0.0f);
      e0 = __builtin_amdgcn_mfma_f32_16x16x32_bf16(kf0, qf[0][0], e0, 0, 0, 0);
      e0 = __builtin_amdgcn_mfma_f32_16x16x32_bf16(kf1, qf[0][1], e0, 0, 0, 0);
      e1 = __builtin_amdgcn_mfma_f32_16x16x32_bf16(kf0, qf[1][0], e1, 0, 0, 0);
      e1 = __builtin_amdgcn_mfma_f32_16x16x32_bf16(kf1, qf[1][1], e1, 0, 0, 0);
      {
        float p0_ = __expf(e0[0]), p1_ = __expf(e0[1]);
        float p2_ = __expf(e0[2]), p3_ = __expf(e0[3]);
        la0 += (p0_ + p1_) + (p2_ + p3_);
        *(uint2*)&Ps[buf][w * 32 + l15][jt * 16 + quad * 4] =
            make_uint2(pack2(p0_, p1_), pack2(p2_, p3_));
      }
      {
        float p0_ = __expf(e1[0]), p1_ = __expf(e1[1]);
        float p2_ = __expf(e1[2]), p3_ = __expf(e1[3]);
        la1 += (p0_ + p1_) + (p2_ + p3_);
        *(uint2*)&Ps[buf][w * 32 + 16 + l15][jt * 16 + quad * 4] =
            make_uint2(pack2(p0_, p1_), pack2(p2_, p3_));
      }
    }
    // barrier: Ps[buf] published; implicit vmcnt(0) drain completes V stage
    __syncthreads();

    // ---- PV: A = P (LDS, all 128 i), B = V (LDS, own 64-c slice) ----
    __builtin_amdgcn_s_setprio(1);
#pragma unroll
    for (int kc = 0; kc < 4; kc++) {
      bfv8 pa[4];
#pragma unroll
      for (int mt = 0; mt < 4; mt++)
        pa[mt] = ld8(&Ps[buf][mt * 32 + l31][kc * 16 + h * 8]);
      bfv8 vb[2];
#pragma unroll
      for (int nt = 0; nt < 2; nt++)
        vb[nt] = *(const bfv8*)&vsw[(nt * 32 + l31) * 64 + (((kc * 2 + h) ^ swz) << 3)];
#pragma unroll
      for (int mt = 0; mt < 4; mt++)
#pragma unroll
        for (int nt = 0; nt < 2; nt++)
          acc[mt][nt] = __builtin_amdgcn_mfma_f32_32x32x16_bf16(pa[mt], vb[nt], acc[mt][nt], 0, 0, 0);
    }
    __builtin_amdgcn_s_setprio(0);
    // pin: stage must not be hoisted above the Vs ds_reads it overwrites
    __builtin_amdgcn_sched_barrier(0);
    if (j0 + 64 < N_) stage_v(p0, vsw, j0 + 64);   // async prefetch next tile
  }

  la0 += __shfl_xor(la0, 16, 64);
  la0 += __shfl_xor(la0, 32, 64);
  la1 += __shfl_xor(la1, 16, 64);
  la1 += __shfl_xor(la1, 32, 64);
  if (lane < 16) {
    invl[w * 32 + l15]      = 1.0f / la0;
    invl[w * 32 + 16 + l15] = 1.0f / la1;
  }
  __syncthreads();

  const float gam = gamma[0];
#pragma unroll
  for (int mt = 0; mt < 4; mt++)
#pragma unroll
    for (int nt = 0; nt < 2; nt++) {
      int c = cbase + nt * 32 + l31;
#pragma unroll
      for (int g = 0; g < 4; g++) {
        int ib = mt * 32 + g * 8 + h * 4;
        f4 il = *(const f4*)&invl[ib];
        size_t off = ((size_t)(b * C_) + c) * N_ + i0 + ib;
        f4 xv = *(const f4*)&x[off];
        f4 o;
#pragma unroll
        for (int r = 0; r < 4; r++)
          o[r] = xv[r] + gam * acc[mt][nt][g * 4 + r] * il[r];
        *(f4*)&out[off] = o;
      }
    }
}

extern "C" void kernel_launch(void* const* d_in, const int* in_sizes, int n_in,
                              void* d_out, int out_size, void* d_ws, size_t ws_size,
                              hipStream_t stream) {
  const float* x     = (const float*)d_in[0];
  const float* Wq    = (const float*)d_in[1];
  const float* bq    = (const float*)d_in[2];
  const float* Wk    = (const float*)d_in[3];
  const float* bk    = (const float*)d_in[4];
  const float* Wv    = (const float*)d_in[5];
  const float* bv    = (const float*)d_in[6];
  const float* gamma = (const float*)d_in[7];
  float* out = (float*)d_out;

  u16* wsu = (u16*)d_ws;
  u16* Qb  = wsu;                                   // B*N*D
  u16* Kb  = Qb  + (size_t)B_ * N_ * D_;            // B*N*D
  u16* Vb  = Kb  + (size_t)B_ * N_ * D_;            // B*C*N
  u16* Wqb = Vb  + (size_t)B_ * C_ * N_;            // D*C
  u16* Wkb = Wqb + (size_t)D_ * C_;                 // D*C
  u16* Wvb = Wkb + (size_t)D_ * C_;                 // C*C

  conv_all<<<dim3(320), 256, 0, stream>>>(Wq, Wk, Wv, Wqb, Wkb, Wvb);
  proj_all<<<dim3(B_, N_ / 64), 256, 0, stream>>>(x, Wqb, Wkb, bq, bk, Wvb, bv, Qb, Kb, Vb);
  attn<<<dim3(B_, N_ / 128, 2), 256, 0, stream>>>(x, Qb, Kb, Vb, gamma, out);
}